// Round 11
// baseline (225.017 us; speedup 1.0000x reference)
//
#include <hip/hip_runtime.h>
#include <hip/hip_bf16.h>

// GCN 2-layer: h1 = relu(Ahat @ (x@W1) + b1); out = Ahat @ (h1@W2) + b2
// Ahat = D^-1/2 (A + I) D^-1/2.
//
// Pipeline (zero global atomics):
//   k_hist/k_scan_cols/k_scan_totals/k_scatter: deterministic bucket partition
//     (bucket = dst>>6) via per-block LDS histograms.
//   k_csr: per bucket -> pair-aligned sentinel-padded src lists (ssrcp),
//     qbeg/qcnt, dinv; zeroes hs row n; guard pair ssrcp[0..1] = {n,n}.
//   k_tw: W1,W2 -> bf16 transposed WT[n][k] (one tiny launch).
//   k_gemm_mfma: 64x64 tile via mfma_f32_16x16x32_bf16; A-frag
//     A[m=lane&15][k=quad*8+j] from LDS xl (pitch 40), B-frag (sym. layout)
//     from LDS wl (pitch K+8); C col=lane&15,row=quad*4+reg; epilogue
//     hs = bf16(dinv * acc).
//   k_agg: wave per node; dual-edge gathers; 16-pair sentinel-padded batches;
//     layer1 emits bf16 hB (halves agg1 writes + gemm2 reads).
// R3: never funnel E atomics into few global addresses.
// R4: agg needs a huge grid + deep MLP, not per-bucket LDS atomics.
// R5: s_barrier is workgroup-scope; 64-wide scan in wave 0 uses shfl.
// R6: bf16 rows halve gather bytes. R7: 2 edges per gather instr.
// R8: masked full-width batches beat scalar remainder loops.
// R9: sentinel padding kills masks and index clamps.
// R10: fp32 vector GEMM was the top remaining kernel -> bf16 MFMA.

#define NB_MAX 1024  // max buckets (n <= 65535 for ushort src packing)

typedef __attribute__((ext_vector_type(8))) short bf16x8;
typedef __attribute__((ext_vector_type(4))) float f32x4;

__device__ inline unsigned short f2bf(float f) {      // RNE fp32 -> bf16
    unsigned u = __builtin_bit_cast(unsigned, f);
    return (unsigned short)((u + 0x7FFFu + ((u >> 16) & 1u)) >> 16);
}

// ---- 1. per-block bucket histogram ----------------------------------------

__global__ __launch_bounds__(256) void k_hist(const int* __restrict__ ei, int E,
                                              int nb, int chunk,
                                              int* __restrict__ histT) {
    __shared__ int h[NB_MAX];
    for (int i = threadIdx.x; i < nb; i += 256) h[i] = 0;
    __syncthreads();
    int e0 = blockIdx.x * chunk, e1 = min(E, e0 + chunk);
    for (int e = e0 + threadIdx.x; e < e1; e += 256)
        atomicAdd(&h[ei[E + e] >> 6], 1);          // LDS atomic
    __syncthreads();
    for (int b = threadIdx.x; b < nb; b += 256)
        histT[b * 256 + blockIdx.x] = h[b];        // [bucket][block]
}

// ---- 2. scan each bucket's 256 per-block counts ---------------------------

__global__ __launch_bounds__(256) void k_scan_cols(int* __restrict__ histT,
                                                   int* __restrict__ total) {
    __shared__ int sm[256];
    int b = blockIdx.x, t = threadIdx.x;
    int v = histT[b * 256 + t];
    sm[t] = v;
    __syncthreads();
    for (int off = 1; off < 256; off <<= 1) {
        int u = (t >= off) ? sm[t - off] : 0;
        __syncthreads();
        sm[t] += u;
        __syncthreads();
    }
    histT[b * 256 + t] = sm[t] - v;                // exclusive within bucket
    if (t == 255) total[b] = sm[255];
}

// ---- 3. scan bucket totals -> bucket bases --------------------------------

__global__ __launch_bounds__(1024) void k_scan_totals(const int* __restrict__ total,
                                                      int* __restrict__ base, int nb) {
    __shared__ int sm[1024];
    int t = threadIdx.x;
    int v = (t < nb) ? total[t] : 0;
    sm[t] = v;
    __syncthreads();
    for (int off = 1; off < 1024; off <<= 1) {
        int u = (t >= off) ? sm[t - off] : 0;
        __syncthreads();
        sm[t] += u;
        __syncthreads();
    }
    if (t < nb) base[t] = sm[t] - v;               // exclusive
    if (t == nb - 1) base[nb] = sm[t];             // total E
}

// ---- 4. scatter packed edges into bucket-grouped order --------------------

__global__ __launch_bounds__(256) void k_scatter(const int* __restrict__ ei, int E,
                                                 int nb, int chunk,
                                                 const int* __restrict__ histT,
                                                 const int* __restrict__ base,
                                                 unsigned* __restrict__ packed) {
    __shared__ int cur[NB_MAX];
    for (int b = threadIdx.x; b < nb; b += 256)
        cur[b] = base[b] + histT[b * 256 + blockIdx.x];
    __syncthreads();
    int e0 = blockIdx.x * chunk, e1 = min(E, e0 + chunk);
    for (int e = e0 + threadIdx.x; e < e1; e += 256) {
        int s = ei[e], d = ei[E + e];
        int pos = atomicAdd(&cur[d >> 6], 1);      // LDS atomic
        packed[pos] = (unsigned)s | ((unsigned)(d & 63) << 16);
    }
}

// ---- 5. per-bucket padded CSR: qbeg/qcnt (pair units), dinv, ssrcp --------

__global__ __launch_bounds__(256) void k_csr(const unsigned* __restrict__ packed,
                                             const int* __restrict__ base,
                                             int n,
                                             int* __restrict__ qbeg,
                                             int* __restrict__ qcnt,
                                             float* __restrict__ dinv,
                                             unsigned short* __restrict__ ssrcp,
                                             unsigned short* __restrict__ hs1,
                                             unsigned short* __restrict__ hs2) {
    __shared__ int cnt[64];
    __shared__ int cur[64];
    const int b = blockIdx.x, t = threadIdx.x;
    const int p0 = base[b], p1 = base[b + 1];
    if (t < 64) cnt[t] = 0;
    __syncthreads();
    for (int p = p0 + t; p < p1; p += 256)
        atomicAdd(&cnt[(packed[p] >> 16) & 63], 1);
    __syncthreads();
    if (t < 64) {                      // wave 0: shuffle scan over padded degs
        int deg = cnt[t];
        int pdeg = (deg + 1) & ~1;     // even-padded degree
        int sum = pdeg;
#pragma unroll
        for (int d = 1; d < 64; d <<= 1) {
            int u = __shfl_up(sum, d, 64);
            if (t >= d) sum += u;
        }
        int excl = sum - pdeg;                       // even
        int pb = (2 + p0 + 128 * b + 1) & ~1;        // even bucket base
        int start = pb + excl;                       // even
        int node = (b << 6) + t;
        if (node < n) {
            qbeg[node] = start >> 1;                 // pair units (>= 1)
            qcnt[node] = pdeg >> 1;
            dinv[node] = 1.0f / sqrtf((float)(deg + 1));  // +1 self-loop
        }
        cur[t] = start;
    }
    __syncthreads();
    for (int p = p0 + t; p < p1; p += 256) {
        unsigned k = packed[p];
        int pos = atomicAdd(&cur[(k >> 16) & 63], 1);
        ssrcp[pos] = (unsigned short)(k & 0xFFFFu);  // ~4 KB window scatter
    }
    __syncthreads();
    if (t < 64 && (cnt[t] & 1))                      // sentinel pad to even
        ssrcp[cur[t]] = (unsigned short)n;
    if (b == 0) {                                    // zero row n + guard pair
        if (t < 64) {
            hs1[(size_t)n * 64 + t] = 0;
            hs2[(size_t)n * 64 + t] = 0;
        }
        if (t == 0) {
            ssrcp[0] = (unsigned short)n;
            ssrcp[1] = (unsigned short)n;
        }
    }
}

// ---- 5b. transpose weights to bf16 WT[n][k] --------------------------------

__global__ __launch_bounds__(256) void k_tw(const float* __restrict__ W1,
                                            const float* __restrict__ W2,
                                            unsigned short* __restrict__ W1T,
                                            unsigned short* __restrict__ W2T) {
    int t = threadIdx.x;
    int nn = t & 63, kb = t >> 6;
    if (blockIdx.x == 0) {
        for (int k = kb; k < 256; k += 4)
            W1T[nn * 256 + k] = f2bf(W1[k * 64 + nn]);   // coalesced reads
    } else {
        for (int k = kb; k < 64; k += 4)
            W2T[nn * 64 + k] = f2bf(W2[k * 64 + nn]);
    }
}

// ---- GEMM (MFMA): HS[n,64] = bf16( dinv[:,None] * (X[n,K] @ W[K,64]) ) -----
// Block 256 = 4 waves; tile 64 rows x 64 cols; wave w = rows w*16..w*16+15.
// A-frag: A[m=lane&15][k=quad*8+j] b128 from xl (pitch 40 ushort = 80 B).
// B-frag: B[n=lane&15][k=quad*8+j] b128 from wl (pitch K+8, 16B-aligned).
// C: col=lane&15, row=quad*4+reg (verified layout).

template <int K, bool XBF16>
__global__ __launch_bounds__(256) void k_gemm_mfma(const void* __restrict__ Xv,
                                                   const unsigned short* __restrict__ WT,
                                                   const float* __restrict__ dinv,
                                                   unsigned short* __restrict__ HS,
                                                   int n) {
    __shared__ unsigned short xl[64][40];        // 64 rows x 32 k, pitch 80 B
    __shared__ unsigned short wl[64][K + 8];     // WT staged, pitch 16B-aligned

    const int t = threadIdx.x;
    const int lane = t & 63, w = t >> 6;
    const int m = lane & 15, quad = lane >> 4;
    const int row0 = blockIdx.x * 64;

    // stage all of WT once (coalesced 16 B copies)
    for (int idx = t; idx < 64 * (K / 8); idx += 256) {
        int r = idx / (K / 8), seg = idx % (K / 8);
        *(uint4*)&wl[r][seg * 8] = *(const uint4*)(WT + r * K + seg * 8);
    }

    f32x4 acc[4];
#pragma unroll
    for (int c = 0; c < 4; ++c) acc[c] = (f32x4)(0.0f);

    for (int k0 = 0; k0 < K; k0 += 32) {
        __syncthreads();   // also covers the initial wl staging
        if (XBF16) {
            const unsigned short* Xb = (const unsigned short*)Xv;
            int r = t >> 2, sg = t & 3;
            int gr = row0 + r;
            uint4 v = {0u, 0u, 0u, 0u};
            if (gr < n)
                v = *(const uint4*)(Xb + (size_t)gr * K + k0 + sg * 8);
            *(uint4*)&xl[r][sg * 8] = v;
        } else {
            const float* Xf = (const float*)Xv;
#pragma unroll
            for (int i = 0; i < 2; ++i) {
                int idx = i * 256 + t;
                int r = idx >> 3, f4 = idx & 7;
                int gr = row0 + r;
                float4 v = make_float4(0.f, 0.f, 0.f, 0.f);
                if (gr < n)
                    v = *(const float4*)(Xf + (size_t)gr * K + k0 + f4 * 4);
                ushort4 pk;
                pk.x = f2bf(v.x); pk.y = f2bf(v.y);
                pk.z = f2bf(v.z); pk.w = f2bf(v.w);
                *(ushort4*)&xl[r][f4 * 4] = pk;
            }
        }
        __syncthreads();

        bf16x8 aF = *(const bf16x8*)&xl[w * 16 + m][quad * 8];
#pragma unroll
        for (int c = 0; c < 4; ++c) {
            bf16x8 bF = *(const bf16x8*)&wl[c * 16 + m][k0 + quad * 8];
            acc[c] = __builtin_amdgcn_mfma_f32_16x16x32_bf16(aF, bF, acc[c],
                                                             0, 0, 0);
        }
    }

#pragma unroll
    for (int reg = 0; reg < 4; ++reg) {
        int row = row0 + w * 16 + quad * 4 + reg;
        if (row < n) {
            float dv = dinv[row];
#pragma unroll
            for (int c = 0; c < 4; ++c)
                HS[(size_t)row * 64 + c * 16 + m] = f2bf(acc[c][reg] * dv);
        }
    }
}

// ---- 6. aggregation: out[i] = dinv[i]*(sum_src hs[src] + hs[i]) + b -------
// Wave per node; dual-edge gathers; 16-pair sentinel-padded batches.
// L1: relu + bf16 output (hB). L2: fp32 output (d_out).

template <bool L1>
__global__ void k_agg(const unsigned short* __restrict__ hs,  // n+1 rows
                      const int* __restrict__ qbeg,
                      const int* __restrict__ qcnt,
                      const unsigned short* __restrict__ ssrcp,
                      const float* __restrict__ dinv,
                      const float* __restrict__ bias,
                      void* __restrict__ outv, int n) {
    int node = blockIdx.x * 4 + (threadIdx.x >> 6);
    if (node >= n) return;
    node = __builtin_amdgcn_readfirstlane(node);   // SGPR -> scalar loads
    const int lane = threadIdx.x & 63;
    const int half = lane >> 5;       // lo/hi edge of the pair
    const int cp   = lane & 31;       // channel pair: ch 2cp, 2cp+1

    const unsigned* hsu = (const unsigned*)hs;     // row = 32 uints (128 B)
    const unsigned* ssu = (const unsigned*)ssrcp;  // src pairs

    const int q0 = qbeg[node];
    const int m  = qcnt[node];

    // epilogue operands issued early, in flight during the gather loop
    const unsigned sv = hsu[node * 32 + cp];
    const float dv = dinv[node];
    const float2 bv = *(const float2*)(bias + 2 * cp);

    float ax = 0.f, ay = 0.f;
    int qb = 0;
    for (; qb + 16 <= m; qb += 16) {               // full batches: no selects
        unsigned ss[16];
#pragma unroll
        for (int j = 0; j < 16; ++j) ss[j] = ssu[q0 + qb + j];
        unsigned v[16];
#pragma unroll
        for (int j = 0; j < 16; ++j) {
            int s = half ? (int)(ss[j] >> 16) : (int)(ss[j] & 0xFFFFu);
            v[j] = hsu[s * 32 + cp];
        }
#pragma unroll
        for (int j = 0; j < 16; ++j) {
            ax += __builtin_bit_cast(float, v[j] << 16);
            ay += __builtin_bit_cast(float, v[j] & 0xFFFF0000u);
        }
    }
    const int rem = m - qb;
    if (rem) {                                     // one tail batch, SALU sel
        unsigned ss[16];
#pragma unroll
        for (int j = 0; j < 16; ++j) {
            int q = (j < rem) ? (q0 + qb + j) : 0; // 0 = {n,n} guard pair
            ss[j] = ssu[q];
        }
        unsigned v[16];
#pragma unroll
        for (int j = 0; j < 16; ++j) {
            int s = half ? (int)(ss[j] >> 16) : (int)(ss[j] & 0xFFFFu);
            v[j] = hsu[s * 32 + cp];
        }
#pragma unroll
        for (int j = 0; j < 16; ++j) {
            ax += __builtin_bit_cast(float, v[j] << 16);
            ay += __builtin_bit_cast(float, v[j] & 0xFFFF0000u);
        }
    }

    // combine the two halves
    ax += __shfl_xor(ax, 32, 64);
    ay += __shfl_xor(ay, 32, 64);

    // epilogue: self-loop + scale + bias; lanes 0..31 store the 64-ch row
    float rx = dv * (ax + __builtin_bit_cast(float, sv << 16)) + bv.x;
    float ry = dv * (ay + __builtin_bit_cast(float, sv & 0xFFFF0000u)) + bv.y;
    if (half == 0) {
        if (L1) {
            rx = fmaxf(rx, 0.f); ry = fmaxf(ry, 0.f);
            ushort2 pk; pk.x = f2bf(rx); pk.y = f2bf(ry);
            *(ushort2*)((unsigned short*)outv + (size_t)node * 64 + 2 * cp) = pk;
        } else {
            *(float2*)((float*)outv + (size_t)node * 64 + 2 * cp) =
                make_float2(rx, ry);
        }
    }
}

// ---- launch ----------------------------------------------------------------

extern "C" void kernel_launch(void* const* d_in, const int* in_sizes, int n_in,
                              void* d_out, int out_size, void* d_ws, size_t ws_size,
                              hipStream_t stream) {
    const float* x  = (const float*)d_in[0];
    const int*   ei = (const int*)d_in[1];
    const float* W1 = (const float*)d_in[2];
    const float* b1 = (const float*)d_in[3];
    const float* W2 = (const float*)d_in[4];
    const float* b2 = (const float*)d_in[5];

    const int n = in_sizes[0] / 256;   // 50000 (< 65536: ushort src packing)
    const int E = in_sizes[1] / 2;     // 1600000
    const int nb = (n + 63) >> 6;      // 782 buckets
    const int chunk = (E + 255) / 256;

    // workspace carve-up (256B aligned)
    char* ws = (char*)d_ws;
    auto carve = [&](size_t bytes) {
        void* p = (void*)ws;
        ws += (bytes + 255) & ~(size_t)255;
        return p;
    };
    int*            histT  = (int*)carve((size_t)nb * 256 * 4);
    int*            total  = (int*)carve((size_t)nb * 4);
    int*            base   = (int*)carve((size_t)(nb + 1) * 4);
    unsigned*       packed = (unsigned*)carve((size_t)E * 4);
    unsigned short* ssrcp  = (unsigned short*)carve(((size_t)E + 128 * nb + 256) * 2);
    int*            qbeg   = (int*)carve((size_t)n * 4);
    int*            qcnt   = (int*)carve((size_t)n * 4);
    float*          dinv   = (float*)carve((size_t)n * 4);
    unsigned short* W1T    = (unsigned short*)carve(64 * 256 * 2);
    unsigned short* W2T    = (unsigned short*)carve(64 * 64 * 2);
    unsigned short* hs1    = (unsigned short*)carve((size_t)(n + 1) * 64 * 2);
    unsigned short* hB     = (unsigned short*)carve((size_t)n * 64 * 2);
    unsigned short* hs2    = (unsigned short*)carve((size_t)(n + 1) * 64 * 2);

    k_hist<<<256, 256, 0, stream>>>(ei, E, nb, chunk, histT);
    k_scan_cols<<<nb, 256, 0, stream>>>(histT, total);
    k_scan_totals<<<1, 1024, 0, stream>>>(total, base, nb);
    k_scatter<<<256, 256, 0, stream>>>(ei, E, nb, chunk, histT, base, packed);
    k_csr<<<nb, 256, 0, stream>>>(packed, base, n, qbeg, qcnt, dinv, ssrcp,
                                  hs1, hs2);
    k_tw<<<2, 256, 0, stream>>>(W1, W2, W1T, W2T);

    const int nbG = (n + 63) / 64;

    // layer 1: hs1 = bf16(dinv*(x@W1)) ; hB = bf16(relu(agg + b1))
    k_gemm_mfma<256, false><<<nbG, 256, 0, stream>>>(x, W1T, dinv, hs1, n);
    k_agg<true><<<(n + 3) / 4, 256, 0, stream>>>(hs1, qbeg, qcnt, ssrcp, dinv,
                                                 b1, hB, n);

    // layer 2: hs2 = bf16(dinv*(hB@W2)) ; out = agg + b2 (fp32)
    k_gemm_mfma<64, true><<<nbG, 256, 0, stream>>>(hB, W2T, dinv, hs2, n);
    k_agg<false><<<(n + 3) / 4, 256, 0, stream>>>(hs2, qbeg, qcnt, ssrcp, dinv,
                                                  b2, d_out, n);
}